// Round 1
// 472.766 us; speedup vs baseline: 1.3366x; 1.3366x over previous
//
#include <hip/hip_runtime.h>
#include <math.h>

#ifndef M_PI
#define M_PI 3.14159265358979323846
#endif

#define B_DIM 8
#define S_DIM 8
#define T_DIM 4096
#define CIN   128
#define COUT  256
#define KT    9
#define NK    5

#define TPAD  (T_DIM + 8)                                  // 4104 padded rows per (b,s)
#define WEFF_SHORTS (S_DIM * KT * COUT * CIN)              // 2,359,296
#define XS_SHORTS   ((size_t)B_DIM * S_DIM * TPAD * CIN)   // 33,619,968
#define WS_NEEDED_BYTES ((size_t)WEFF_SHORTS * 2 + XS_SHORTS * 2)   // ~72 MB

typedef __attribute__((ext_vector_type(8))) short bf16x8;   // 8 bf16 = 4 VGPRs
typedef __attribute__((ext_vector_type(4))) float f32x4;    // MFMA accum

__device__ __forceinline__ unsigned short f2bf(float f) {
    union { float f; unsigned u; } v; v.f = f;
    unsigned u = v.u;
    u += 0x7fffu + ((u >> 16) & 1u);        // RNE to bf16
    return (unsigned short)(u >> 16);
}

// async global->LDS, 16B per lane; LDS dest = base + lane*16 (wave-uniform base)
__device__ __forceinline__ void gll16(const void* gsrc, void* ldst) {
    __builtin_amdgcn_global_load_lds(
        (__attribute__((address_space(1))) void*)(void*)gsrc,
        (__attribute__((address_space(3))) void*)ldst, 16, 0, 0);
}

// ============================ PASS 1: prep =================================
// part A: xs[b][s][tpad][ci] bf16 = fused 3-tap scale conv, zero pad rows,
//         16B-chunk XOR-swizzled by (tpad&7)
// part B: weff[s][dt][co][ci] bf16, 16B-chunk XOR-swizzled by (co&7)
struct PrepArgs { float wt[S_DIM * KT * NK]; float bs[9]; };

#define XS_RB       257                    // ceil(4104/16) row-blocks per (b,s)
#define N_XS_BLOCKS (64 * XS_RB)           // 16448
#define N_W_BLOCKS  (S_DIM * KT * 4)       // 288

__global__ __launch_bounds__(256) void prep_kernel(
    const float* __restrict__ x, const float* __restrict__ coeffs,
    const float* __restrict__ cscale, unsigned short* __restrict__ weff,
    unsigned short* __restrict__ xs, PrepArgs args)
{
    const int tid = threadIdx.x;
    int bid = blockIdx.x;
    if (bid < N_XS_BLOCKS) {
        // decode: b in low bits so default XCD round-robin groups by batch
        const int b  = bid & 7;
        const int s  = (bid >> 3) & 7;
        const int rb = bid >> 6;
        const int bs = b * 8 + s;
        const int sm = (s > 0) ? s - 1 : 0;
        const int sp = (s < 7) ? s + 1 : 7;

        const float c0 = cscale[0], c1 = cscale[1], c2 = cscale[2];
        const float w0 = args.bs[0]*c0 + args.bs[1]*c1 + args.bs[2]*c2;
        const float w1 = args.bs[3]*c0 + args.bs[4]*c1 + args.bs[5]*c2;
        const float w2 = args.bs[6]*c0 + args.bs[7]*c1 + args.bs[8]*c2;

        const int tpad  = rb * 16 + (tid >> 4);
        const int chunk = tid & 15;                 // 16B chunk = 8 ci
        if (tpad >= TPAD) return;

        uint4 v = make_uint4(0u, 0u, 0u, 0u);
        const int t = tpad - 4;
        if (t >= 0 && t < T_DIM) {
            const size_t roff = (size_t)t * CIN + (chunk << 3);
            const float* p0 = x + (size_t)(b * S_DIM + sm) * T_DIM * CIN + roff;
            const float* p1 = x + (size_t)(b * S_DIM + s ) * T_DIM * CIN + roff;
            const float* p2 = x + (size_t)(b * S_DIM + sp) * T_DIM * CIN + roff;
            float4 a0 = *(const float4*)(p0),     a1 = *(const float4*)(p0 + 4);
            float4 b0 = *(const float4*)(p1),     b1 = *(const float4*)(p1 + 4);
            float4 d0 = *(const float4*)(p2),     d1 = *(const float4*)(p2 + 4);
            unsigned short* pv = (unsigned short*)&v;
            pv[0] = f2bf(w0*a0.x + w1*b0.x + w2*d0.x);
            pv[1] = f2bf(w0*a0.y + w1*b0.y + w2*d0.y);
            pv[2] = f2bf(w0*a0.z + w1*b0.z + w2*d0.z);
            pv[3] = f2bf(w0*a0.w + w1*b0.w + w2*d0.w);
            pv[4] = f2bf(w0*a1.x + w1*b1.x + w2*d1.x);
            pv[5] = f2bf(w0*a1.y + w1*b1.y + w2*d1.y);
            pv[6] = f2bf(w0*a1.z + w1*b1.z + w2*d1.z);
            pv[7] = f2bf(w0*a1.w + w1*b1.w + w2*d1.w);
        }
        const int csw = chunk ^ (tpad & 7);         // pre-swizzle for gll+ds_read
        *(uint4*)&xs[((size_t)bs * TPAD + tpad) * CIN + (csw << 3)] = v;
    } else {
        const int wb  = bid - N_XS_BLOCKS;
        const int sdt = wb % (S_DIM * KT);
        const int ci0 = (wb / (S_DIM * KT)) << 5;
        const int co  = tid;
        float w[NK];
#pragma unroll
        for (int k = 0; k < NK; ++k) w[k] = args.wt[sdt * NK + k];

        for (int cc = 0; cc < 32; cc += 8) {
            uint4 pack;
            unsigned short* p = (unsigned short*)&pack;
#pragma unroll
            for (int e = 0; e < 8; ++e) {
                int ci = ci0 + cc + e;
                float acc = 0.f;
#pragma unroll
                for (int k = 0; k < NK; ++k)
                    acc += w[k] * coeffs[((size_t)k * CIN + ci) * COUT + co];
                p[e] = f2bf(acc);
            }
            const int csw = ((ci0 + cc) >> 3) ^ (co & 7);
            *(uint4*)&weff[((size_t)sdt * COUT + co) * CIN + (csw << 3)] = pack;
        }
    }
}

// ============================ PASS 2: GEMM =================================
// 128t x 128co tile, 4 waves of 64x64; As staged once (window, all 9 dt);
// Bs restaged per dt; all staging via global_load_lds; swizzled ds_read_b128.
#define BM 128
#define BN 128
#define AROWS 136
#define NWG (32 * 2 * 64)     // 4096, divisible by 8 -> bijective XCD swizzle

__global__ __launch_bounds__(256, 2) void conv_kernel(
    const unsigned short* __restrict__ xs, const unsigned short* __restrict__ weff,
    float* __restrict__ out)
{
    __shared__ unsigned short As[AROWS * CIN];   // 34816 B, linear pitch 128
    __shared__ unsigned short Bs[BN * CIN];      // 32768 B -> 66 KB total, 2 blk/CU

    const int tid  = threadIdx.x;
    const int lane = tid & 63, wave = tid >> 6;
    const int lrow = lane & 15, quad = lane >> 4;

    // XCD-bijective swizzle: each XCD gets a contiguous 512-block chunk
    const int id = blockIdx.x;
    const int w  = (id & 7) * (NWG >> 3) + (id >> 3);
    const int t0      = (w & 31) * BM;           // t fastest within chunk
    const int co_base = ((w >> 5) & 1) * BN;
    const int bsix    = w >> 6;
    const int s       = bsix & 7;

    const int wr = (wave >> 1) * 64;
    const int wc = (wave & 1) * 64;

    // ---- stage As window (t0-4 .. t0+131 in padded coords): 34 x 1KB linear
    const unsigned short* asrc = xs + ((size_t)bsix * TPAD + t0) * CIN;
    for (int g = wave; g < 34; g += 4)
        gll16(asrc + (g << 9) + (lane << 3), (char*)As + (g << 10));

    f32x4 acc[4][4];
#pragma unroll
    for (int i = 0; i < 4; ++i)
#pragma unroll
        for (int j = 0; j < 4; ++j)
            acc[i][j] = (f32x4){0.f, 0.f, 0.f, 0.f};

    const int bkey = (wc + lrow) & 7;            // Bs XOR key (const: co_base%8==0)
    const unsigned short* wbase = weff + ((size_t)(s * KT) * COUT + co_base) * CIN;

    for (int dt = 0; dt < KT; ++dt) {
        __syncthreads();                          // prev-dt consumers done (+As drain @dt0)
        const unsigned short* wdt = wbase + (size_t)dt * COUT * CIN;
        for (int g = wave; g < 32; g += 4)        // 32 KB Bs slice, linear
            gll16(wdt + (g << 9) + (lane << 3), (char*)Bs + (g << 10));
        __syncthreads();                          // compiler drains vmcnt(0) here

        const int ar   = wr + lrow + dt;
        const int akey = ar & 7;                  // (ar+16i)&7 == ar&7
#pragma unroll
        for (int k = 0; k < 4; ++k) {             // ci chunks of 32
            bf16x8 a[4], bb[4];
#pragma unroll
            for (int i = 0; i < 4; ++i)
                a[i] = *(const bf16x8*)&As[((ar + (i << 4)) << 7) +
                                           ((((k << 2) + quad) ^ akey) << 3)];
#pragma unroll
            for (int j = 0; j < 4; ++j)
                bb[j] = *(const bf16x8*)&Bs[((wc + (j << 4) + lrow) << 7) +
                                            ((((k << 2) + quad) ^ bkey) << 3)];
#pragma unroll
            for (int i = 0; i < 4; ++i)
#pragma unroll
                for (int j = 0; j < 4; ++j)
                    acc[i][j] = __builtin_amdgcn_mfma_f32_16x16x32_bf16(
                        a[i], bb[j], acc[i][j], 0, 0, 0);
        }
    }

    // ---- epilogue: C/D layout col=lane&15, row=quad*4+v
    float* obase = out + ((size_t)bsix * T_DIM + t0) * COUT + co_base;
#pragma unroll
    for (int i = 0; i < 4; ++i) {
#pragma unroll
        for (int j = 0; j < 4; ++j) {
            const int r0 = wr + (i << 4) + (quad << 2);
            const int c  = wc + (j << 4) + lrow;
#pragma unroll
            for (int v = 0; v < 4; ++v)
                obase[(size_t)(r0 + v) * COUT + c] = acc[i][j][v];
        }
    }
}

// ===================== FALLBACK (previous verified path) ====================
struct WtArgs { float wt[S_DIM * KT * NK]; };
struct BsArgs { float bs[9]; };

__global__ __launch_bounds__(256) void weights_fb(
    const float* __restrict__ coeffs, unsigned short* __restrict__ weff, WtArgs args)
{
    const int sdt = blockIdx.x;
    const int ci0 = blockIdx.y * 32;
    const int co  = threadIdx.x;
    float w[NK];
#pragma unroll
    for (int k = 0; k < NK; ++k) w[k] = args.wt[sdt * NK + k];
    for (int cc = 0; cc < 32; cc += 8) {
        uint4 pack;
        unsigned short* p = (unsigned short*)&pack;
#pragma unroll
        for (int e = 0; e < 8; ++e) {
            int ci = ci0 + cc + e;
            float acc = 0.f;
#pragma unroll
            for (int k = 0; k < NK; ++k)
                acc += w[k] * coeffs[((size_t)k * CIN + ci) * COUT + co];
            p[e] = f2bf(acc);
        }
        *(uint4*)&weff[((size_t)sdt * COUT + co) * CIN + ci0 + cc] = pack;
    }
}

#define PITCH 136

__global__ __launch_bounds__(256, 2) void conv_fb(
    const float* __restrict__ x, const unsigned short* __restrict__ weff,
    const float* __restrict__ cscale, float* __restrict__ out, BsArgs args)
{
    __shared__ unsigned short As[AROWS * PITCH];
    __shared__ unsigned short Bs[BN * PITCH];

    const int tid = threadIdx.x;
    const int lane = tid & 63, wave = tid >> 6;
    const int lrow = lane & 15, quad = lane >> 4;
    const int wr = (wave >> 1) * 64;
    const int wc = (wave & 1) * 64;

    const int t0      = blockIdx.x * BM;
    const int co_base = blockIdx.y * BN;
    const int bsix    = blockIdx.z;
    const int b = bsix >> 3, s = bsix & 7;
    const int sm = (s > 0) ? s - 1 : 0;
    const int sp = (s < 7) ? s + 1 : 7;

    const float c0 = cscale[0], c1 = cscale[1], c2 = cscale[2];
    const float w0 = args.bs[0]*c0 + args.bs[1]*c1 + args.bs[2]*c2;
    const float w1 = args.bs[3]*c0 + args.bs[4]*c1 + args.bs[5]*c2;
    const float w2 = args.bs[6]*c0 + args.bs[7]*c1 + args.bs[8]*c2;

    const float* x0 = x + (size_t)(b * S_DIM + sm) * T_DIM * CIN;
    const float* x1 = x + (size_t)(b * S_DIM + s ) * T_DIM * CIN;
    const float* x2 = x + (size_t)(b * S_DIM + sp) * T_DIM * CIN;

    for (int idx = tid; idx < AROWS * 32; idx += 256) {
        int row = idx >> 5;
        int c4  = (idx & 31) << 2;
        int tt  = t0 - 4 + row;
        ushort4 v = make_ushort4(0, 0, 0, 0);
        if (tt >= 0 && tt < T_DIM) {
            size_t off = (size_t)tt * CIN + c4;
            float4 a = *(const float4*)(x0 + off);
            float4 bb = *(const float4*)(x1 + off);
            float4 c = *(const float4*)(x2 + off);
            v.x = f2bf(w0*a.x + w1*bb.x + w2*c.x);
            v.y = f2bf(w0*a.y + w1*bb.y + w2*c.y);
            v.z = f2bf(w0*a.z + w1*bb.z + w2*c.z);
            v.w = f2bf(w0*a.w + w1*bb.w + w2*c.w);
        }
        *(ushort4*)&As[row * PITCH + c4] = v;
    }

    f32x4 acc[4][4];
#pragma unroll
    for (int i = 0; i < 4; ++i)
#pragma unroll
        for (int j = 0; j < 4; ++j)
            acc[i][j] = (f32x4){0.f, 0.f, 0.f, 0.f};

    for (int dt = 0; dt < KT; ++dt) {
        __syncthreads();
        const unsigned short* wdt =
            weff + (((size_t)(s * KT + dt)) * COUT + co_base) * CIN;
        for (int idx = tid; idx < BN * 16; idx += 256) {
            int row = idx >> 4;
            int c8  = (idx & 15) << 3;
            uint4 v = *(const uint4*)(wdt + (size_t)row * CIN + c8);
            *(uint4*)&Bs[row * PITCH + c8] = v;
        }
        __syncthreads();

#pragma unroll
        for (int ci0 = 0; ci0 < CIN; ci0 += 32) {
            bf16x8 a[4], bfr[4];
#pragma unroll
            for (int i = 0; i < 4; ++i)
                a[i] = *(const bf16x8*)&As[(wr + 16*i + lrow + dt) * PITCH + ci0 + quad*8];
#pragma unroll
            for (int j = 0; j < 4; ++j)
                bfr[j] = *(const bf16x8*)&Bs[(wc + 16*j + lrow) * PITCH + ci0 + quad*8];
#pragma unroll
            for (int i = 0; i < 4; ++i)
#pragma unroll
                for (int j = 0; j < 4; ++j)
                    acc[i][j] = __builtin_amdgcn_mfma_f32_16x16x32_bf16(
                        a[i], bfr[j], acc[i][j], 0, 0, 0);
        }
    }

    float* obase = out + ((size_t)bsix * T_DIM + t0) * COUT + co_base;
#pragma unroll
    for (int i = 0; i < 4; ++i) {
#pragma unroll
        for (int j = 0; j < 4; ++j) {
            int r0 = wr + 16*i + quad*4;
            int c  = wc + 16*j + lrow;
#pragma unroll
            for (int v = 0; v < 4; ++v)
                obase[(size_t)(r0 + v) * COUT + c] = acc[i][j][v];
        }
    }
}

// ================================ host =====================================
extern "C" void kernel_launch(void* const* d_in, const int* in_sizes, int n_in,
                              void* d_out, int out_size, void* d_ws, size_t ws_size,
                              hipStream_t stream)
{
    const float* x      = (const float*)d_in[0];   // (8,8,4096,128) fp32
    const float* coeffs = (const float*)d_in[1];   // (5,128,256) fp32
    const float* cscale = (const float*)d_in[2];   // (3,) fp32
    float* out = (float*)d_out;                    // (8,8,4096,256) fp32

    static const double SC[8] = {-1.5, -1.0, -0.5, 0.0, 0.5, 1.0, 1.5, 2.0};
    float wt[S_DIM * KT * NK];
    float bsv[9];
    for (int i = 0; i < S_DIM; ++i) {
        double alpha = SC[i];
        double scale = pow(2.0, alpha);
        double us    = pow(2.0, -alpha);
        for (int j = 0; j < KT; ++j) {
            double t = (j - 4.0) / 4.0;
            double u = t * us;
            double mask = (fabs(u) <= 1.0) ? 1.0 : 0.0;
            for (int k = 0; k < NK; ++k) {
                int freq = (k + 1) / 2;
                double arg = M_PI * (double)freq * u;
                double v = (k % 2 == 0) ? cos(arg) : sin(arg);
                wt[(i * KT + j) * NK + k] = (float)(mask * v * scale);
            }
        }
    }
    for (int j = 0; j < 3; ++j) {
        double t = (double)(j - 1);
        for (int k = 0; k < 3; ++k) {
            int freq = (k + 1) / 2;
            double arg = M_PI * (double)freq * t;
            bsv[j * 3 + k] = (float)((k % 2 == 0) ? cos(arg) : sin(arg));
        }
    }

    unsigned short* weff = (unsigned short*)d_ws;

    if (ws_size >= WS_NEEDED_BYTES) {
        unsigned short* xs = weff + WEFF_SHORTS;
        PrepArgs pargs;
        for (int i = 0; i < S_DIM * KT * NK; ++i) pargs.wt[i] = wt[i];
        for (int i = 0; i < 9; ++i) pargs.bs[i] = bsv[i];
        prep_kernel<<<dim3(N_XS_BLOCKS + N_W_BLOCKS), dim3(256), 0, stream>>>(
            x, coeffs, cscale, weff, xs, pargs);
        conv_kernel<<<dim3(NWG), dim3(256), 0, stream>>>(xs, weff, out);
    } else {
        WtArgs wargs;
        for (int i = 0; i < S_DIM * KT * NK; ++i) wargs.wt[i] = wt[i];
        BsArgs bargs;
        for (int i = 0; i < 9; ++i) bargs.bs[i] = bsv[i];
        weights_fb<<<dim3(S_DIM * KT, 4), dim3(256), 0, stream>>>(coeffs, weff, wargs);
        conv_fb<<<dim3(T_DIM / BM, COUT / BN, B_DIM * S_DIM), dim3(256), 0, stream>>>(
            x, weff, cscale, out, bargs);
    }
}